// Round 1
// baseline (462.735 us; speedup 1.0000x reference)
//
#include <hip/hip_runtime.h>
#include <hip/hip_bf16.h>
#include <math.h>

// B=64, C=16, F=2048, J=25 ; EMBED=64, CLASSES=5, NJ=12
// stats: s2=max, s3=q25(pos 511.75), s4=xs[1023], s5=q75(pos 1535.25),
//        s6=mean, s7=std(ddof=1), s8=max-min, s9=kurtosis
// stat1/W1/b1 path is dead code in the reference. features[...,24] unused.
//
// Round-7: occupancy push. Theory: 228us >> ~70us VALU-issue floor ->
// latency-bound at 42% occupancy (33KB LDS -> 4 blocks/CU). Changes:
//  (a) LDS halved to 2 regions (16,448B) via 2-round staging: float4 loads
//      (4B-aligned vector type; row stride 100B so 16B align impossible),
//      .x/.y staged now, .z/.w held in 16 VGPRs and staged after round 1
//      is consumed. Same cacheline-request count as round-6 staging.
//  (b) bitonic extended to stage 11 (full sort; lane^32 via ds_bpermute).
//      Sorted dump + merge-path DELETED: all 7 order stats sit at
//      compile-time (lane,reg) slots, extracted with constant-lane shfl.
//  (c) __launch_bounds__(256,8): cap 64 VGPR -> 8 blocks/CU (32 waves/CU).

#define F_LEN 2048
#define JTOT 25
#define STATS_PER_BC 192 // 16 s * 12 j
#define LP 2056          // LDS words per j-region (2048 + 8 so stride%32==8)

typedef float f4a __attribute__((ext_vector_type(4), aligned(4)));

// Word swizzle: rotate each 32-word row by 4*(row&7) words, WRAPPED in-row.
__device__ __forceinline__ int swz(int i) {
  return (i & ~31) | ((i + ((i >> 5) << 2)) & 31);
}

// ds_swizzle with immediate xor pattern (BitMode: offset=(xor<<10)|0x1F).
template <int PAT>
__device__ __forceinline__ float ds_swz(float v) {
  return __int_as_float(
      __builtin_amdgcn_ds_swizzle(__float_as_int(v), PAT));
}
// xor-partner for lane-mask lm in {1,2,4,8,16,32}; folds under full unroll.
// lm<=16 stays within the 32-lane half (ds_swizzle); lm=32 uses bpermute.
__device__ __forceinline__ float swzxor(float v, const int lm,
                                        const int addr32) {
  switch (lm) {
    case 1:  return ds_swz<0x041F>(v);
    case 2:  return ds_swz<0x081F>(v);
    case 4:  return ds_swz<0x101F>(v);
    case 8:  return ds_swz<0x201F>(v);
    case 16: return ds_swz<0x401F>(v);
    default: return __int_as_float(
        __builtin_amdgcn_ds_bpermute(addr32, __float_as_int(v)));
  }
}
// full 64-lane sum: 5 swizzles + 1 bpermute (addr32 = (lane^32)<<2).
__device__ __forceinline__ float wave_sum(float v, int addr32) {
  v += ds_swz<0x041F>(v);
  v += ds_swz<0x081F>(v);
  v += ds_swz<0x101F>(v);
  v += ds_swz<0x201F>(v);
  v += ds_swz<0x401F>(v);
  v += __int_as_float(
      __builtin_amdgcn_ds_bpermute(addr32, __float_as_int(v)));
  return v;
}

// Read one staged region as 8 conflict-free ds_read_b128 (rotated cols).
// Element mapping proven: x[e] = array[lane*32 + e]  (blocked layout).
__device__ __forceinline__ void read_x(const float* wlds, int lane,
                                       float* x) {
  const float4* src4 = (const float4*)wlds;
#pragma unroll
  for (int q = 0; q < 8; ++q) {
    float4 v = src4[lane * 8 + ((lane + q) & 7)];
    x[4 * q] = v.x;
    x[4 * q + 1] = v.y;
    x[4 * q + 2] = v.z;
    x[4 * q + 3] = v.w;
  }
}

__global__ __launch_bounds__(256, 8) void stat_kernel(
    const float* __restrict__ Fp, float* __restrict__ stat2) {
  __shared__ float lds[2 * LP]; // 16,448 B -> 8 blocks/CU
  const int g = blockIdx.x;     // 0..6143
  const int xcd = g & 7;
  const int mm = g >> 3;
  const int bc = xcd * 128 + mm / 6;
  const int grp = mm % 6;
  const int t = threadIdx.x;
  const int w = t >> 6;
  const int lane = t & 63;
  const int addr32 = ((lane ^ 32) << 2);
  const int j0 = grp * 4; // block handles arrays j0..j0+3; wave w sorts j0+w

  // ---- staging: 8x float4/thread (all 4 j-cols), 2 LDS rounds ----
  float vz[8], vw[8];
  const int rot = (t + ((t >> 5) << 2)) & 31; // swz(f) with f=it*256+t:
  float* p0 = lds + (t & ~31) + rot;          //  word = it*256 + (t&~31)+rot
  {
    const float* bbase = Fp + (size_t)bc * F_LEN * JTOT + j0;
#pragma unroll
    for (int it = 0; it < 8; ++it) {
      const int f = it * 256 + t;
      f4a v = *reinterpret_cast<const f4a*>(bbase + (size_t)f * JTOT);
      p0[it * 256] = v.x;          // region 0 = array j0
      p0[LP + it * 256] = v.y;     // region 1 = array j0+1
      vz[it] = v.z;
      vw[it] = v.w;
    }
  }
  __syncthreads();

  float x[32];
  if (w < 2) read_x(lds + w * LP, lane, x);
  __syncthreads();

  {
#pragma unroll
    for (int it = 0; it < 8; ++it) {
      p0[it * 256] = vz[it];       // region 0 = array j0+2
      p0[LP + it * 256] = vw[it];  // region 1 = array j0+3
    }
  }
  __syncthreads();
  if (w >= 2) read_x(lds + (w - 2) * LP, lane, x);
  // no further barriers: waves 0/1 already sorting.

  // ---- moments (two-pass central) ----
  float sum = 0.f;
#pragma unroll
  for (int e = 0; e < 32; ++e) sum += x[e];
  sum = wave_sum(sum, addr32);
  const float m = sum * (1.0f / 2048.0f);

  float c2 = 0.f, c4 = 0.f;
#pragma unroll
  for (int e = 0; e < 32; ++e) {
    float d = x[e] - m;
    float dd = d * d;
    c2 += dd;
    c4 += dd * dd;
  }
  c2 = wave_sum(c2, addr32);
  c4 = wave_sum(c4, addr32);
  const float var = c2 * (1.0f / 2047.0f); // ddof=1
  const float sd = sqrtf(var);
  const float kurt = (c4 * (1.0f / 2048.0f)) / (var * var) - 3.0f;

  // ---- bitonic stages 1..4: in-register, direction by e (compile-time) ----
#pragma unroll
  for (int kp = 1; kp <= 4; ++kp) {
    const int k = 1 << kp;
#pragma unroll
    for (int jp = kp - 1; jp >= 0; --jp) {
      const int st = 1 << jp;
#pragma unroll
      for (int e = 0; e < 32; ++e) {
        if ((e & st) == 0) {
          const bool up = ((e & k) == 0);
          float a = x[e], b = x[e + st];
          float lo2 = fminf(a, b), hi2 = fmaxf(a, b);
          x[e] = up ? lo2 : hi2;
          x[e + st] = up ? hi2 : lo2;
        }
      }
    }
  }

  // ---- stages 5..11: running sign-state Fst = direction ^ role ----
  // idx = lane*32 + e; stage-11 direction d = (lane>>6)&1 == 0 for every
  // lane, so after the end-of-stage flip values are TRUE ascending and no
  // post-loop unflip is needed.
  unsigned Fst = 0u;
#pragma unroll
  for (int kp = 5; kp <= 11; ++kp) {
    const unsigned d = ((lane >> (kp - 5)) & 1) ? 0x80000000u : 0u;
#pragma unroll
    for (int jp = kp - 1; jp >= 5; --jp) {
      const int lm = 1 << (jp - 5); // 1,2,4,8,16,32
      const unsigned r = ((lane >> (jp - 5)) & 1) ? 0x80000000u : 0u;
      const unsigned tgt = d ^ r;
      const unsigned fl = tgt ^ Fst;
      Fst = tgt;
#pragma unroll
      for (int e = 0; e < 32; ++e)
        x[e] = __uint_as_float(__float_as_uint(x[e]) ^ fl);
#pragma unroll
      for (int e = 0; e < 32; ++e) {
        float o = swzxor(x[e], lm, addr32);
        x[e] = fminf(x[e], -o); // uniform: keeps min (role-0) / -max (role-1)
      }
    }
    {
      const unsigned fl = d ^ Fst;
      Fst = d;
#pragma unroll
      for (int e = 0; e < 32; ++e)
        x[e] = __uint_as_float(__float_as_uint(x[e]) ^ fl);
    }
#pragma unroll
    for (int jp = 4; jp >= 0; --jp) {
      const int st = 1 << jp;
#pragma unroll
      for (int e = 0; e < 32; ++e) {
        if ((e & st) == 0) {
          float a = x[e], b = x[e + st];
          x[e] = fminf(a, b);
          x[e + st] = fmaxf(a, b);
        }
      }
    }
  }
  // Fst == 0 here (d==0 at kp=11 for all lanes): values are true ascending.

  // ---- extraction: xs[k] lives at lane k>>5, reg k&31 (compile-time) ----
  const float mn = __shfl(x[0], 0, 64);     // xs[0]
  const float a511 = __shfl(x[31], 15, 64); // xs[511]
  const float a512 = __shfl(x[0], 16, 64);  // xs[512]
  const float amed = __shfl(x[31], 31, 64); // xs[1023]
  const float a1535 = __shfl(x[31], 47, 64);
  const float a1536 = __shfl(x[0], 48, 64);
  const float mx = __shfl(x[31], 63, 64);   // xs[2047]

  if (lane == 0) {
    const float q25 = 0.25f * a511 + 0.75f * a512;   // pos = 511.75
    const float q75 = 0.75f * a1535 + 0.25f * a1536; // pos = 1535.25
    const int j = j0 + w;
    const int jj = (j < 12) ? j : j - 12;
    const int sb = (j < 12) ? 0 : 8;
    float st8[8] = {mx, q25, amed, q75, m, sd, mx - mn, kurt};
    float* o = stat2 + (bc * 16 + sb) * 12 + jj;
#pragma unroll
    for (int s2 = 0; s2 < 8; ++s2) o[s2 * 12] = st8[s2];
  }
}

// ---------------------------------------------------------------------------
// Kernel B: fuse (einsum over c,j with W2 + b2) then logits (@ Wl.T + bl).
// ---------------------------------------------------------------------------
__global__ __launch_bounds__(256) void fuse_kernel(
    const float* __restrict__ stat2, const float* __restrict__ W2,
    const float* __restrict__ b2, const float* __restrict__ Wl,
    const float* __restrict__ bl, float* __restrict__ out) {
  __shared__ float s_stat[16 * STATS_PER_BC];
  __shared__ float s_flat[1024];
  __shared__ float s_red[4];

  const int b = blockIdx.x;
  const int t = threadIdx.x;

  for (int idx = t; idx < 16 * STATS_PER_BC; idx += 256)
    s_stat[idx] = stat2[b * (16 * STATS_PER_BC) + idx];
  __syncthreads();

  const int e = t & 63;
  const int q = t >> 6;
  float acc[4] = {0.f, 0.f, 0.f, 0.f};
  for (int c = 0; c < 16; ++c) {
    const float* wrow = W2 + (e * 16 + c) * 12;
    const float* srow = s_stat + c * STATS_PER_BC;
#pragma unroll
    for (int jj = 0; jj < 12; ++jj) {
      const float wv = wrow[jj];
#pragma unroll
      for (int ss = 0; ss < 4; ++ss)
        acc[ss] += srow[(q * 4 + ss) * 12 + jj] * wv;
    }
  }
  const float bb = b2[e];
#pragma unroll
  for (int ss = 0; ss < 4; ++ss)
    s_flat[e * 16 + q * 4 + ss] = acc[ss] + bb;
  __syncthreads();

  for (int k = 0; k < 5; ++k) {
    float p = 0.f;
    for (int i = t; i < 1024; i += 256) p += s_flat[i] * Wl[k * 1024 + i];
#pragma unroll
    for (int off = 32; off; off >>= 1) p += __shfl_down(p, off, 64);
    if ((t & 63) == 0) s_red[t >> 6] = p;
    __syncthreads();
    if (t == 0)
      out[b * 5 + k] = s_red[0] + s_red[1] + s_red[2] + s_red[3] + bl[k];
    __syncthreads();
  }
}

extern "C" void kernel_launch(void* const* d_in, const int* in_sizes, int n_in,
                              void* d_out, int out_size, void* d_ws,
                              size_t ws_size, hipStream_t stream) {
  const float* Fp = (const float*)d_in[0];
  // d_in[1] = W1, d_in[2] = b1 -> dead code in reference, unused.
  const float* W2 = (const float*)d_in[3];
  const float* b2 = (const float*)d_in[4];
  const float* Wl = (const float*)d_in[5];
  const float* bl = (const float*)d_in[6];
  float* out = (float*)d_out;

  float* stat2 = (float*)d_ws; // 1024*192 floats = 768 KB scratch

  stat_kernel<<<6144, 256, 0, stream>>>(Fp, stat2);
  fuse_kernel<<<64, 256, 0, stream>>>(stat2, W2, b2, Wl, bl, out);
}

// Round 2
// 461.701 us; speedup vs baseline: 1.0022x; 1.0022x over previous
//
#include <hip/hip_runtime.h>
#include <hip/hip_bf16.h>
#include <math.h>

// B=64, C=16, F=2048, J=25 ; EMBED=64, CLASSES=5, NJ=12
// stats: s2=max, s3=q25(pos 511.75), s4=xs[1023], s5=q75(pos 1535.25),
//        s6=mean, s7=std(ddof=1), s8=max-min, s9=kurtosis
// stat1/W1/b1 path is dead code in the reference. features[...,24] unused.
//
// Round-8: DS-pipe relief + fuse-tail collapse.
//  Theory from r7 counters: sort is DS-issue-bound (~950 ds_swizzle/wave on
//  the single per-CU LDS unit ~= 220us, matching dur). Occupancy was never
//  the limit (80% occ + 2x HBM spill traffic only cost +50us).
//  (a) cross-lane exchanges lm<=8 now VALU DPP (4 pipes/CU vs 1 DS unit):
//      lm=1,2 quad_perm; lm=8 row_ror:8 (==xor8, direction-agnostic);
//      lm=4 bank-masked row_shl:4 (banks 0,2: lane+4) + row_shr:4
//      (banks 1,3: lane-4). lm=16 keeps ds_swizzle, lm=32 ds_bpermute.
//  (b) fuse tail (~185us, uncoalesced W2 @ 1 blk/CU) replaced by
//      prep_kernel (M[k,c,s,j]=sum_e Wl[k,e*16+s]*W2[e,c,j], C[k]) +
//      coalesced logits_kernel: logits = M . stat + C.
//  (c) plain __launch_bounds__(256): r7's (256,8) cap caused 71MB of
//      scratch spill (VGPR 32 + WRITE_SIZE 71MB in counters).

#define F_LEN 2048
#define JTOT 25
#define STATS_PER_BC 192 // 16 s * 12 j
#define LP 2056          // LDS words per j-region (2048 + 8 so stride%32==8)

typedef float f4a __attribute__((ext_vector_type(4), aligned(4)));

// ds_swizzle with immediate xor pattern (BitMode: offset=(xor<<10)|0x1F).
template <int PAT>
__device__ __forceinline__ float ds_swz(float v) {
  return __int_as_float(
      __builtin_amdgcn_ds_swizzle(__float_as_int(v), PAT));
}

// DPP with compile-time ctrl/bank mask (row_mask always 0xF, bc=false).
template <int CTRL, int BANK>
__device__ __forceinline__ int upd_dpp(int old_, int src) {
  return __builtin_amdgcn_update_dpp(old_, src, CTRL, 0xF, BANK, false);
}

// Partner value at lane^lm. lm in {1,2,4,8}: pure VALU DPP (off the DS
// pipe). lm=16: ds_swizzle. lm=32: ds_bpermute with precomputed address.
__device__ __forceinline__ float xpartner(float v, const int lm,
                                          const int addr32) {
  const int vi = __float_as_int(v);
  switch (lm) {
    case 1:  // quad_perm [1,0,3,2]
      return __int_as_float(upd_dpp<0xB1, 0xF>(vi, vi));
    case 2:  // quad_perm [2,3,0,1]
      return __int_as_float(upd_dpp<0x4E, 0xF>(vi, vi));
    case 4: {
      // banks 0,2 (lane bit2==0): row_shl:4 -> reads lane+4
      // banks 1,3 (lane bit2==1): row_shr:4 -> reads lane-4
      const int t1 = upd_dpp<0x104, 0x5>(vi, vi);
      const int t2 = upd_dpp<0x114, 0xA>(t1, vi);
      return __int_as_float(t2);
    }
    case 8:  // row_ror:8 == xor8 within 16-row (symmetric, convention-proof)
      return __int_as_float(upd_dpp<0x128, 0xF>(vi, vi));
    case 16:
      return ds_swz<0x401F>(v);
    default:
      return __int_as_float(
          __builtin_amdgcn_ds_bpermute(addr32, vi));
  }
}

// full 64-lane sum via xpartner butterfly (only 2 DS ops now).
__device__ __forceinline__ float wave_sum(float v, int addr32) {
  v += xpartner(v, 1, addr32);
  v += xpartner(v, 2, addr32);
  v += xpartner(v, 4, addr32);
  v += xpartner(v, 8, addr32);
  v += xpartner(v, 16, addr32);
  v += xpartner(v, 32, addr32);
  return v;
}

// Read one staged region as 8 conflict-free ds_read_b128 (rotated cols).
// Element mapping proven: x[e] = array[lane*32 + e]  (blocked layout).
__device__ __forceinline__ void read_x(const float* wlds, int lane,
                                       float* x) {
  const float4* src4 = (const float4*)wlds;
#pragma unroll
  for (int q = 0; q < 8; ++q) {
    float4 v = src4[lane * 8 + ((lane + q) & 7)];
    x[4 * q] = v.x;
    x[4 * q + 1] = v.y;
    x[4 * q + 2] = v.z;
    x[4 * q + 3] = v.w;
  }
}

__global__ __launch_bounds__(256) void stat_kernel(
    const float* __restrict__ Fp, float* __restrict__ stat2) {
  __shared__ float lds[2 * LP]; // 16,448 B
  const int g = blockIdx.x;     // 0..6143
  const int xcd = g & 7;
  const int mm = g >> 3;
  const int bc = xcd * 128 + mm / 6;
  const int grp = mm % 6;
  const int t = threadIdx.x;
  const int w = t >> 6;
  const int lane = t & 63;
  const int addr32 = ((lane ^ 32) << 2);
  const int j0 = grp * 4; // block handles arrays j0..j0+3; wave w sorts j0+w

  // ---- staging: 8x float4/thread (all 4 j-cols), 2 LDS rounds ----
  float vz[8], vw[8];
  const int rot = (t + ((t >> 5) << 2)) & 31; // swz(f) with f=it*256+t
  float* p0 = lds + (t & ~31) + rot;
  {
    const float* bbase = Fp + (size_t)bc * F_LEN * JTOT + j0;
#pragma unroll
    for (int it = 0; it < 8; ++it) {
      const int f = it * 256 + t;
      f4a v = *reinterpret_cast<const f4a*>(bbase + (size_t)f * JTOT);
      p0[it * 256] = v.x;      // region 0 = array j0
      p0[LP + it * 256] = v.y; // region 1 = array j0+1
      vz[it] = v.z;
      vw[it] = v.w;
    }
  }
  __syncthreads();

  float x[32];
  if (w < 2) read_x(lds + w * LP, lane, x);
  __syncthreads();

  {
#pragma unroll
    for (int it = 0; it < 8; ++it) {
      p0[it * 256] = vz[it];      // region 0 = array j0+2
      p0[LP + it * 256] = vw[it]; // region 1 = array j0+3
    }
  }
  __syncthreads();
  if (w >= 2) read_x(lds + (w - 2) * LP, lane, x);
  // no further barriers: waves 0/1 already sorting.

  // ---- moments (two-pass central) ----
  float sum = 0.f;
#pragma unroll
  for (int e = 0; e < 32; ++e) sum += x[e];
  sum = wave_sum(sum, addr32);
  const float m = sum * (1.0f / 2048.0f);

  float c2 = 0.f, c4 = 0.f;
#pragma unroll
  for (int e = 0; e < 32; ++e) {
    float d = x[e] - m;
    float dd = d * d;
    c2 += dd;
    c4 += dd * dd;
  }
  c2 = wave_sum(c2, addr32);
  c4 = wave_sum(c4, addr32);
  const float var = c2 * (1.0f / 2047.0f); // ddof=1
  const float sd = sqrtf(var);
  const float kurt = (c4 * (1.0f / 2048.0f)) / (var * var) - 3.0f;

  // ---- bitonic stages 1..4: in-register, direction by e (compile-time) ----
#pragma unroll
  for (int kp = 1; kp <= 4; ++kp) {
    const int k = 1 << kp;
#pragma unroll
    for (int jp = kp - 1; jp >= 0; --jp) {
      const int st = 1 << jp;
#pragma unroll
      for (int e = 0; e < 32; ++e) {
        if ((e & st) == 0) {
          const bool up = ((e & k) == 0);
          float a = x[e], b = x[e + st];
          float lo2 = fminf(a, b), hi2 = fmaxf(a, b);
          x[e] = up ? lo2 : hi2;
          x[e + st] = up ? hi2 : lo2;
        }
      }
    }
  }

  // ---- stages 5..11: running sign-state Fst = direction ^ role ----
  // idx = lane*32 + e; stage-11 direction d==0 for every lane, so after the
  // end-of-stage flip values are TRUE ascending; no post-loop unflip.
  unsigned Fst = 0u;
#pragma unroll
  for (int kp = 5; kp <= 11; ++kp) {
    const unsigned d = ((lane >> (kp - 5)) & 1) ? 0x80000000u : 0u;
#pragma unroll
    for (int jp = kp - 1; jp >= 5; --jp) {
      const int lm = 1 << (jp - 5); // 1,2,4,8,16,32
      const unsigned r = ((lane >> (jp - 5)) & 1) ? 0x80000000u : 0u;
      const unsigned tgt = d ^ r;
      const unsigned fl = tgt ^ Fst;
      Fst = tgt;
#pragma unroll
      for (int e = 0; e < 32; ++e)
        x[e] = __uint_as_float(__float_as_uint(x[e]) ^ fl);
#pragma unroll
      for (int e = 0; e < 32; ++e) {
        float o = xpartner(x[e], lm, addr32);
        x[e] = fminf(x[e], -o); // uniform: keeps min (role-0) / -max (role-1)
      }
    }
    {
      const unsigned fl = d ^ Fst;
      Fst = d;
#pragma unroll
      for (int e = 0; e < 32; ++e)
        x[e] = __uint_as_float(__float_as_uint(x[e]) ^ fl);
    }
#pragma unroll
    for (int jp = 4; jp >= 0; --jp) {
      const int st = 1 << jp;
#pragma unroll
      for (int e = 0; e < 32; ++e) {
        if ((e & st) == 0) {
          float a = x[e], b = x[e + st];
          x[e] = fminf(a, b);
          x[e + st] = fmaxf(a, b);
        }
      }
    }
  }
  // Fst == 0 here: values are true ascending across idx = lane*32+e.

  // ---- extraction: xs[k] lives at lane k>>5, reg k&31 (compile-time) ----
  const float mn = __shfl(x[0], 0, 64);     // xs[0]
  const float a511 = __shfl(x[31], 15, 64); // xs[511]
  const float a512 = __shfl(x[0], 16, 64);  // xs[512]
  const float amed = __shfl(x[31], 31, 64); // xs[1023]
  const float a1535 = __shfl(x[31], 47, 64);
  const float a1536 = __shfl(x[0], 48, 64);
  const float mx = __shfl(x[31], 63, 64);   // xs[2047]

  if (lane == 0) {
    const float q25 = 0.25f * a511 + 0.75f * a512;   // pos = 511.75
    const float q75 = 0.75f * a1535 + 0.25f * a1536; // pos = 1535.25
    const int j = j0 + w;
    const int jj = (j < 12) ? j : j - 12;
    const int sb = (j < 12) ? 0 : 8;
    float st8[8] = {mx, q25, amed, q75, m, sd, mx - mn, kurt};
    float* o = stat2 + (bc * 16 + sb) * 12 + jj;
#pragma unroll
    for (int s2 = 0; s2 < 8; ++s2) o[s2 * 12] = st8[s2];
  }
}

// ---------------------------------------------------------------------------
// prep: M[k,c,s,j] = sum_e Wl[k,e*16+s] * W2[e,c,j]   (5*16*16*12 = 15360)
//       C[k] = bl[k] + sum_e b2[e] * sum_s Wl[k,e*16+s]
// logits[b,k] = sum_i M[k,i] * stat2[b,i] + C[k],  i = c*192 + s*12 + j
// ---------------------------------------------------------------------------
__global__ __launch_bounds__(256) void prep_kernel(
    const float* __restrict__ W2, const float* __restrict__ b2,
    const float* __restrict__ Wl, const float* __restrict__ bl,
    float* __restrict__ M, float* __restrict__ C) {
  const int g = blockIdx.x;
  const int t = threadIdx.x;
  if (g < 60) {
    const int id = g * 256 + t; // k*3072 + c*192 + s*12 + j
    const int k = id / 3072;
    const int r = id % 3072;
    const int c = r / 192;
    const int s = (r % 192) / 12;
    const int j = r % 12;
    const float* wl = Wl + k * 1024 + s;
    const float* w2 = W2 + c * 12 + j;
    float acc = 0.f;
#pragma unroll 8
    for (int e = 0; e < 64; ++e) acc += wl[e * 16] * w2[e * 192];
    M[id] = acc;
  } else if (t < 64) { // one wave computes C[0..4]
    const int e = t;
    const int addr32 = ((e ^ 32) << 2);
    for (int k = 0; k < 5; ++k) {
      const float* wl = Wl + k * 1024 + e * 16;
      float rs = 0.f;
#pragma unroll
      for (int s = 0; s < 16; ++s) rs += wl[s];
      float v = wave_sum(rs * b2[e], addr32);
      if (e == 0) C[k] = v + bl[k];
    }
  }
}

__global__ __launch_bounds__(256) void logits_kernel(
    const float* __restrict__ stat2, const float* __restrict__ M,
    const float* __restrict__ C, float* __restrict__ out) {
  __shared__ float s_red[20];
  const int b = blockIdx.x;
  const int t = threadIdx.x;
  const int lane = t & 63;
  const int w = t >> 6;
  const int addr32 = ((lane ^ 32) << 2);

  float acc[5] = {0.f, 0.f, 0.f, 0.f, 0.f};
#pragma unroll
  for (int ii = 0; ii < 12; ++ii) {
    const int i = ii * 256 + t;
    const float s = stat2[b * 3072 + i];
#pragma unroll
    for (int k = 0; k < 5; ++k) acc[k] += s * M[k * 3072 + i];
  }
#pragma unroll
  for (int k = 0; k < 5; ++k) acc[k] = wave_sum(acc[k], addr32);
  if (lane == 0) {
#pragma unroll
    for (int k = 0; k < 5; ++k) s_red[w * 5 + k] = acc[k];
  }
  __syncthreads();
  if (t < 5)
    out[b * 5 + t] =
        s_red[t] + s_red[5 + t] + s_red[10 + t] + s_red[15 + t] + C[t];
}

extern "C" void kernel_launch(void* const* d_in, const int* in_sizes, int n_in,
                              void* d_out, int out_size, void* d_ws,
                              size_t ws_size, hipStream_t stream) {
  const float* Fp = (const float*)d_in[0];
  // d_in[1] = W1, d_in[2] = b1 -> dead code in reference, unused.
  const float* W2 = (const float*)d_in[3];
  const float* b2 = (const float*)d_in[4];
  const float* Wl = (const float*)d_in[5];
  const float* bl = (const float*)d_in[6];
  float* out = (float*)d_out;

  float* stat2 = (float*)d_ws;      // 1024*192 floats = 768 KB
  float* M = stat2 + 196608;        // 15360 floats
  float* C = M + 15360;             // 5 floats

  prep_kernel<<<61, 256, 0, stream>>>(W2, b2, Wl, bl, M, C);
  stat_kernel<<<6144, 256, 0, stream>>>(Fp, stat2);
  logits_kernel<<<64, 256, 0, stream>>>(stat2, M, C, out);
}

// Round 3
// 449.252 us; speedup vs baseline: 1.0300x; 1.0277x over previous
//
#include <hip/hip_runtime.h>
#include <hip/hip_bf16.h>
#include <math.h>

// B=64, C=16, F=2048, J=25 ; EMBED=64, CLASSES=5, NJ=12
// stats: s2=max, s3=q25(pos 511.75), s4=xs[1023], s5=q75(pos 1535.25),
//        s6=mean, s7=std(ddof=1), s8=max-min, s9=kurtosis
// stat1/W1/b1 path is dead code in the reference. features[...,24] unused.
//
// Round-9: VGPR unlock + stage-11 removal.
//  r8 post-mortem: VALUBusy ~100% but implied ~13K instr/wave vs ~5K in
//  source. Cause: VGPR_Count=36 (allocator minimized for occupancy) ->
//  element-serial substages, exposed DPP hazards / RAW latency.
//  (a) __launch_bounds__(256,4) (cap 128 VGPR) + batched substage loops
//      (o[32] partner temp) so the scheduler can hide DPP hazards.
//      Tripwire: WRITE_SIZE must stay ~0.8MB (no spill).
//  (b) stage 11 dropped (23% of comparators); r6's PROVEN merge-path
//      selection restored, adapted to 2-region LDS: waves 0/1 dump+merge
//      first, barrier, waves 2/3 reuse the regions. mn/mx LDS reads are
//      inside the gated phase (before the region is overwritten).

#define F_LEN 2048
#define JTOT 25
#define STATS_PER_BC 192 // 16 s * 12 j
#define LP 2056          // LDS words per j-region (2048 + 8 so stride%32==8)

typedef float f4a __attribute__((ext_vector_type(4), aligned(4)));

// Word swizzle: rotate each 32-word row by 4*(row&7) words, WRAPPED in-row.
__device__ __forceinline__ int swz(int i) {
  return (i & ~31) | ((i + ((i >> 5) << 2)) & 31);
}

// ds_swizzle with immediate xor pattern (BitMode: offset=(xor<<10)|0x1F).
template <int PAT>
__device__ __forceinline__ float ds_swz(float v) {
  return __int_as_float(
      __builtin_amdgcn_ds_swizzle(__float_as_int(v), PAT));
}

// DPP with compile-time ctrl/bank mask (row_mask always 0xF, bc=false).
template <int CTRL, int BANK>
__device__ __forceinline__ int upd_dpp(int old_, int src) {
  return __builtin_amdgcn_update_dpp(old_, src, CTRL, 0xF, BANK, false);
}

// Partner value at lane^lm. lm in {1,2,4,8}: pure VALU DPP (off the DS
// pipe). lm=16: ds_swizzle. lm=32: ds_bpermute with precomputed address.
__device__ __forceinline__ float xpartner(float v, const int lm,
                                          const int addr32) {
  const int vi = __float_as_int(v);
  switch (lm) {
    case 1:  // quad_perm [1,0,3,2]
      return __int_as_float(upd_dpp<0xB1, 0xF>(vi, vi));
    case 2:  // quad_perm [2,3,0,1]
      return __int_as_float(upd_dpp<0x4E, 0xF>(vi, vi));
    case 4: {
      // banks 0,2 (lane bit2==0): row_shl:4 -> reads lane+4
      // banks 1,3 (lane bit2==1): row_shr:4 -> reads lane-4
      const int t1 = upd_dpp<0x104, 0x5>(vi, vi);
      const int t2 = upd_dpp<0x114, 0xA>(t1, vi);
      return __int_as_float(t2);
    }
    case 8:  // row_ror:8 == xor8 within 16-row (symmetric, convention-proof)
      return __int_as_float(upd_dpp<0x128, 0xF>(vi, vi));
    case 16:
      return ds_swz<0x401F>(v);
    default:
      return __int_as_float(
          __builtin_amdgcn_ds_bpermute(addr32, vi));
  }
}

// full 64-lane sum via xpartner butterfly (only 2 DS ops).
__device__ __forceinline__ float wave_sum(float v, int addr32) {
  v += xpartner(v, 1, addr32);
  v += xpartner(v, 2, addr32);
  v += xpartner(v, 4, addr32);
  v += xpartner(v, 8, addr32);
  v += xpartner(v, 16, addr32);
  v += xpartner(v, 32, addr32);
  return v;
}

// Read one staged region as 8 conflict-free ds_read_b128 (rotated cols).
// Element mapping proven: x[e] = array[lane*32 + e]  (blocked layout).
__device__ __forceinline__ void read_x(const float* wlds, int lane,
                                       float* x) {
  const float4* src4 = (const float4*)wlds;
#pragma unroll
  for (int q = 0; q < 8; ++q) {
    float4 v = src4[lane * 8 + ((lane + q) & 7)];
    x[4 * q] = v.x;
    x[4 * q + 1] = v.y;
    x[4 * q + 2] = v.z;
    x[4 * q + 3] = v.w;
  }
}

// r6-proven merge-path selection over the two sorted halves in one region:
// [0..1023] ascending, [1024..2047] descending (both via swz layout).
// Lanes 0..4 find ranks {511,512,1023,1535,1536}; lane0 also reads mn/mx.
// ALL LDS reads happen here (caller must gate before region reuse).
__device__ __forceinline__ void merge7(const float* wlds, int lane,
                                       float& val, float& mn, float& mx) {
  const int kk = (lane == 0) ? 511
               : (lane == 1) ? 512
               : (lane == 2) ? 1023
               : (lane == 3) ? 1535 : 1536;
  const int mtot = kk + 1;
  int lo = mtot - 1024; if (lo < 0) lo = 0;
  int hi = (mtot < 1024) ? mtot : 1024;
  for (int it = 0; it < 11; ++it) {
    const bool act = lo < hi;
    const int s = (lo + hi) >> 1;
    const int sa = (s < 1023) ? s : 1023;
    float Av = wlds[swz(sa)];
    Av = (s < 1024) ? Av : INFINITY;
    int bidx = mtot - s - 1;
    bidx = bidx < 0 ? 0 : (bidx > 1023 ? 1023 : bidx);
    const float Bv = wlds[swz(2047 - bidx)];
    const bool gg = act && (Bv > Av);
    if (gg) lo = s + 1;
    else if (act) hi = s;
  }
  {
    const int s = lo;
    const int ia = (s - 1 < 0) ? 0 : s - 1;
    const float fa = wlds[swz(ia)];
    const float fromA = (s > 0) ? fa : -INFINITY;
    const int bi = mtot - s - 1;
    const int ib = (bi < 0) ? 0 : bi;
    const float fb = wlds[swz(2047 - ib)];
    const float fromB = (bi >= 0) ? fb : -INFINITY;
    val = fmaxf(fromA, fromB);
  }
  if (lane == 0) {
    mn = fminf(wlds[swz(0)], wlds[swz(2047)]);
    mx = fmaxf(wlds[swz(1023)], wlds[swz(1024)]);
  }
}

__global__ __launch_bounds__(256, 4) void stat_kernel(
    const float* __restrict__ Fp, float* __restrict__ stat2) {
  __shared__ float lds[2 * LP]; // 16,448 B
  const int g = blockIdx.x;     // 0..6143
  const int xcd = g & 7;
  const int mm = g >> 3;
  const int bc = xcd * 128 + mm / 6;
  const int grp = mm % 6;
  const int t = threadIdx.x;
  const int w = t >> 6;
  const int lane = t & 63;
  const int addr32 = ((lane ^ 32) << 2);
  const int j0 = grp * 4; // block handles arrays j0..j0+3; wave w sorts j0+w

  // ---- staging: 8x float4/thread (all 4 j-cols), 2 LDS rounds ----
  float vz[8], vw[8];
  const int rot = (t + ((t >> 5) << 2)) & 31; // swz(f) with f=it*256+t
  float* p0 = lds + (t & ~31) + rot;
  {
    const float* bbase = Fp + (size_t)bc * F_LEN * JTOT + j0;
#pragma unroll
    for (int it = 0; it < 8; ++it) {
      const int f = it * 256 + t;
      f4a v = *reinterpret_cast<const f4a*>(bbase + (size_t)f * JTOT);
      p0[it * 256] = v.x;      // region 0 = array j0
      p0[LP + it * 256] = v.y; // region 1 = array j0+1
      vz[it] = v.z;
      vw[it] = v.w;
    }
  }
  __syncthreads();

  float x[32];
  if (w < 2) read_x(lds + w * LP, lane, x);
  __syncthreads();

  {
#pragma unroll
    for (int it = 0; it < 8; ++it) {
      p0[it * 256] = vz[it];      // region 0 = array j0+2
      p0[LP + it * 256] = vw[it]; // region 1 = array j0+3
    }
  }
  __syncthreads();
  if (w >= 2) read_x(lds + (w - 2) * LP, lane, x);
  // no further barriers until the dump phase: all waves sort in-register.

  // ---- moments (two-pass central) ----
  float sum = 0.f;
#pragma unroll
  for (int e = 0; e < 32; ++e) sum += x[e];
  sum = wave_sum(sum, addr32);
  const float m = sum * (1.0f / 2048.0f);

  float c2 = 0.f, c4 = 0.f;
#pragma unroll
  for (int e = 0; e < 32; ++e) {
    float d = x[e] - m;
    float dd = d * d;
    c2 += dd;
    c4 += dd * dd;
  }
  c2 = wave_sum(c2, addr32);
  c4 = wave_sum(c4, addr32);
  const float var = c2 * (1.0f / 2047.0f); // ddof=1
  const float sd = sqrtf(var);
  const float kurt = (c4 * (1.0f / 2048.0f)) / (var * var) - 3.0f;

  // ---- bitonic stages 1..4: in-register, direction by e (compile-time) ----
#pragma unroll
  for (int kp = 1; kp <= 4; ++kp) {
    const int k = 1 << kp;
#pragma unroll
    for (int jp = kp - 1; jp >= 0; --jp) {
      const int st = 1 << jp;
#pragma unroll
      for (int e = 0; e < 32; ++e) {
        if ((e & st) == 0) {
          const bool up = ((e & k) == 0);
          float a = x[e], b = x[e + st];
          float lo2 = fminf(a, b), hi2 = fmaxf(a, b);
          x[e] = up ? lo2 : hi2;
          x[e + st] = up ? hi2 : lo2;
        }
      }
    }
  }

  // ---- stages 5..10: running sign-state Fst = direction ^ role ----
  // Batched loops (flip-all / partner-all / min-all) so the scheduler can
  // hide DPP read hazards; o[32] temp needs the (256,4) VGPR headroom.
  unsigned Fst = 0u;
#pragma unroll
  for (int kp = 5; kp <= 10; ++kp) {
    const unsigned d = ((lane >> (kp - 5)) & 1) ? 0x80000000u : 0u;
#pragma unroll
    for (int jp = kp - 1; jp >= 5; --jp) {
      const int lm = 1 << (jp - 5); // 1,2,4,8,16
      const unsigned r = ((lane >> (jp - 5)) & 1) ? 0x80000000u : 0u;
      const unsigned tgt = d ^ r;
      const unsigned fl = tgt ^ Fst;
      Fst = tgt;
      float o[32];
#pragma unroll
      for (int e = 0; e < 32; ++e)
        x[e] = __uint_as_float(__float_as_uint(x[e]) ^ fl);
#pragma unroll
      for (int e = 0; e < 32; ++e) o[e] = xpartner(x[e], lm, addr32);
#pragma unroll
      for (int e = 0; e < 32; ++e)
        x[e] = fminf(x[e], -o[e]); // keeps min (role-0) / -max (role-1)
    }
    {
      const unsigned fl = d ^ Fst;
      Fst = d;
#pragma unroll
      for (int e = 0; e < 32; ++e)
        x[e] = __uint_as_float(__float_as_uint(x[e]) ^ fl);
    }
#pragma unroll
    for (int jp = 4; jp >= 0; --jp) {
      const int st = 1 << jp;
#pragma unroll
      for (int e = 0; e < 32; ++e) {
        if ((e & st) == 0) {
          float a = x[e], b = x[e + st];
          x[e] = fminf(a, b);
          x[e + st] = fmaxf(a, b);
        }
      }
    }
  }
  // unflip (Fst = stage-10 direction = lane>=32): [0..1023] asc, rest desc.
#pragma unroll
  for (int e = 0; e < 32; ++e)
    x[e] = __uint_as_float(__float_as_uint(x[e]) ^ Fst);

  // ---- dump + merge-path in two shifts over the 2 regions ----
  float* wl2 = lds + (w & 1) * LP;
  float val = 0.f, mn = 0.f, mx = 0.f;
  if (w < 2) {
    float4* dst4 = (float4*)wl2;
#pragma unroll
    for (int q = 0; q < 8; ++q) {
      int wq = 8 * lane + ((q + lane) & 7);
      dst4[wq] = make_float4(x[4 * q], x[4 * q + 1], x[4 * q + 2], x[4 * q + 3]);
    }
  }
  __syncthreads();
  if (w < 2) merge7(wl2, lane, val, mn, mx);
  __syncthreads(); // waves 0/1 done reading before regions are reused
  if (w >= 2) {
    float4* dst4 = (float4*)wl2;
#pragma unroll
    for (int q = 0; q < 8; ++q) {
      int wq = 8 * lane + ((q + lane) & 7);
      dst4[wq] = make_float4(x[4 * q], x[4 * q + 1], x[4 * q + 2], x[4 * q + 3]);
    }
  }
  __syncthreads();
  if (w >= 2) merge7(wl2, lane, val, mn, mx);

  // ---- extraction + output (register/global only; no LDS) ----
  const float a511 = __shfl(val, 0, 64);
  const float a512 = __shfl(val, 1, 64);
  const float amed = __shfl(val, 2, 64);
  const float a1535 = __shfl(val, 3, 64);
  const float a1536 = __shfl(val, 4, 64);

  if (lane == 0) {
    const float q25 = 0.25f * a511 + 0.75f * a512;   // pos = 511.75
    const float q75 = 0.75f * a1535 + 0.25f * a1536; // pos = 1535.25
    const int j = j0 + w;
    const int jj = (j < 12) ? j : j - 12;
    const int sb = (j < 12) ? 0 : 8;
    float st8[8] = {mx, q25, amed, q75, m, sd, mx - mn, kurt};
    float* o = stat2 + (bc * 16 + sb) * 12 + jj;
#pragma unroll
    for (int s2 = 0; s2 < 8; ++s2) o[s2 * 12] = st8[s2];
  }
}

// ---------------------------------------------------------------------------
// prep: M[k,c,s,j] = sum_e Wl[k,e*16+s] * W2[e,c,j]   (5*16*16*12 = 15360)
//       C[k] = bl[k] + sum_e b2[e] * sum_s Wl[k,e*16+s]
// logits[b,k] = sum_i M[k,i] * stat2[b,i] + C[k],  i = c*192 + s*12 + j
// ---------------------------------------------------------------------------
__global__ __launch_bounds__(256) void prep_kernel(
    const float* __restrict__ W2, const float* __restrict__ b2,
    const float* __restrict__ Wl, const float* __restrict__ bl,
    float* __restrict__ M, float* __restrict__ C) {
  const int g = blockIdx.x;
  const int t = threadIdx.x;
  if (g < 60) {
    const int id = g * 256 + t; // k*3072 + c*192 + s*12 + j
    const int k = id / 3072;
    const int r = id % 3072;
    const int c = r / 192;
    const int s = (r % 192) / 12;
    const int j = r % 12;
    const float* wl = Wl + k * 1024 + s;
    const float* w2 = W2 + c * 12 + j;
    float acc = 0.f;
#pragma unroll 8
    for (int e = 0; e < 64; ++e) acc += wl[e * 16] * w2[e * 192];
    M[id] = acc;
  } else if (t < 64) { // one wave computes C[0..4]
    const int e = t;
    const int addr32 = ((e ^ 32) << 2);
    for (int k = 0; k < 5; ++k) {
      const float* wl = Wl + k * 1024 + e * 16;
      float rs = 0.f;
#pragma unroll
      for (int s = 0; s < 16; ++s) rs += wl[s];
      float v = wave_sum(rs * b2[e], addr32);
      if (e == 0) C[k] = v + bl[k];
    }
  }
}

__global__ __launch_bounds__(256) void logits_kernel(
    const float* __restrict__ stat2, const float* __restrict__ M,
    const float* __restrict__ C, float* __restrict__ out) {
  __shared__ float s_red[20];
  const int b = blockIdx.x;
  const int t = threadIdx.x;
  const int lane = t & 63;
  const int w = t >> 6;
  const int addr32 = ((lane ^ 32) << 2);

  float acc[5] = {0.f, 0.f, 0.f, 0.f, 0.f};
#pragma unroll
  for (int ii = 0; ii < 12; ++ii) {
    const int i = ii * 256 + t;
    const float s = stat2[b * 3072 + i];
#pragma unroll
    for (int k = 0; k < 5; ++k) acc[k] += s * M[k * 3072 + i];
  }
#pragma unroll
  for (int k = 0; k < 5; ++k) acc[k] = wave_sum(acc[k], addr32);
  if (lane == 0) {
#pragma unroll
    for (int k = 0; k < 5; ++k) s_red[w * 5 + k] = acc[k];
  }
  __syncthreads();
  if (t < 5)
    out[b * 5 + t] =
        s_red[t] + s_red[5 + t] + s_red[10 + t] + s_red[15 + t] + C[t];
}

extern "C" void kernel_launch(void* const* d_in, const int* in_sizes, int n_in,
                              void* d_out, int out_size, void* d_ws,
                              size_t ws_size, hipStream_t stream) {
  const float* Fp = (const float*)d_in[0];
  // d_in[1] = W1, d_in[2] = b1 -> dead code in reference, unused.
  const float* W2 = (const float*)d_in[3];
  const float* b2 = (const float*)d_in[4];
  const float* Wl = (const float*)d_in[5];
  const float* bl = (const float*)d_in[6];
  float* out = (float*)d_out;

  float* stat2 = (float*)d_ws; // 1024*192 floats = 768 KB
  float* M = stat2 + 196608;   // 15360 floats
  float* C = M + 15360;        // 5 floats

  prep_kernel<<<61, 256, 0, stream>>>(W2, b2, Wl, bl, M, C);
  stat_kernel<<<6144, 256, 0, stream>>>(Fp, stat2);
  logits_kernel<<<64, 256, 0, stream>>>(stat2, M, C, out);
}

// Round 5
// 430.947 us; speedup vs baseline: 1.0738x; 1.0425x over previous
//
#include <hip/hip_runtime.h>
#include <hip/hip_bf16.h>
#include <math.h>

// B=64, C=16, F=2048, J=25 ; EMBED=64, CLASSES=5, NJ=12
// stats: s2=max, s3=q25(pos 511.75), s4=xs[1023], s5=q75(pos 1535.25),
//        s6=mean, s7=std(ddof=1), s8=max-min, s9=kurtosis
// stat1/W1/b1 path is dead code in the reference. features[...,24] unused.
//
// Round-10 (resubmit; round-4 bench was an infra failure — "container
// failed twice", no counters): discriminating experiment — TWO arrays
// per wave.
//  r8/r9 post-mortem: compiler pins VGPR=36 and re-serializes every
//  batched-ILP attempt; 261/265/280us across 3 structures, vs 68us VALU
//  issue floor. Hypotheses: H1 element-serial DPP hazard stalls (spare
//  regs=4); H2 I$ thrash (~30KB unrolled body); H3 true issue-bound.
//  This kernel sorts x[32] AND y[32] per wave, substages interleaved:
//  forces >=64 live VGPRs (no serialization possible below), every DPP
//  has an independent twin to fill hazard slots. Same total instr count
//  (waves halved), 2x code size. H1 -> ~150us, H2 -> 350+, H3 -> ~260.
//  Also: 4 regions / 4 waves -> dump+merge wave-private, 3 fewer barriers.
//  Tripwire: WRITE_SIZE ~1MB (no spill); VGPR ~90-110.

#define F_LEN 2048
#define JTOT 25
#define STATS_PER_BC 192 // 16 s * 12 j
#define LP 2056          // LDS words per j-region (2048 + 8 so stride%32==8)

typedef float f4a __attribute__((ext_vector_type(4), aligned(4)));

// Word swizzle: rotate each 32-word row by 4*(row&7) words, WRAPPED in-row.
__device__ __forceinline__ int swz(int i) {
  return (i & ~31) | ((i + ((i >> 5) << 2)) & 31);
}

// ds_swizzle with immediate xor pattern (BitMode: offset=(xor<<10)|0x1F).
template <int PAT>
__device__ __forceinline__ float ds_swz(float v) {
  return __int_as_float(
      __builtin_amdgcn_ds_swizzle(__float_as_int(v), PAT));
}

// DPP with compile-time ctrl/bank mask (row_mask always 0xF, bc=false).
template <int CTRL, int BANK>
__device__ __forceinline__ int upd_dpp(int old_, int src) {
  return __builtin_amdgcn_update_dpp(old_, src, CTRL, 0xF, BANK, false);
}

// Partner value at lane^lm. lm in {1,2,4,8}: pure VALU DPP (off the DS
// pipe). lm=16: ds_swizzle. lm=32: ds_bpermute with precomputed address.
__device__ __forceinline__ float xpartner(float v, const int lm,
                                          const int addr32) {
  const int vi = __float_as_int(v);
  switch (lm) {
    case 1:  // quad_perm [1,0,3,2]
      return __int_as_float(upd_dpp<0xB1, 0xF>(vi, vi));
    case 2:  // quad_perm [2,3,0,1]
      return __int_as_float(upd_dpp<0x4E, 0xF>(vi, vi));
    case 4: {
      // banks 0,2 (lane bit2==0): row_shl:4 -> reads lane+4
      // banks 1,3 (lane bit2==1): row_shr:4 -> reads lane-4
      const int t1 = upd_dpp<0x104, 0x5>(vi, vi);
      const int t2 = upd_dpp<0x114, 0xA>(t1, vi);
      return __int_as_float(t2);
    }
    case 8:  // row_ror:8 == xor8 within 16-row (symmetric, convention-proof)
      return __int_as_float(upd_dpp<0x128, 0xF>(vi, vi));
    case 16:
      return ds_swz<0x401F>(v);
    default:
      return __int_as_float(
          __builtin_amdgcn_ds_bpermute(addr32, vi));
  }
}

// full 64-lane sum via xpartner butterfly.
__device__ __forceinline__ float wave_sum(float v, int addr32) {
  v += xpartner(v, 1, addr32);
  v += xpartner(v, 2, addr32);
  v += xpartner(v, 4, addr32);
  v += xpartner(v, 8, addr32);
  v += xpartner(v, 16, addr32);
  v += xpartner(v, 32, addr32);
  return v;
}

// paired 64-lane sum: two independent reductions interleaved (ILP).
__device__ __forceinline__ void wave_sum2(float& a, float& b, int addr32) {
#pragma unroll
  for (int lm = 1; lm <= 32; lm <<= 1) {
    float pa = xpartner(a, lm, addr32);
    float pb = xpartner(b, lm, addr32);
    a += pa;
    b += pb;
  }
}

// Read one staged region as 8 conflict-free ds_read_b128 (rotated cols).
// Element mapping proven: x[e] = array[lane*32 + e]  (blocked layout).
__device__ __forceinline__ void read_x(const float* wlds, int lane,
                                       float* x) {
  const float4* src4 = (const float4*)wlds;
#pragma unroll
  for (int q = 0; q < 8; ++q) {
    float4 v = src4[lane * 8 + ((lane + q) & 7)];
    x[4 * q] = v.x;
    x[4 * q + 1] = v.y;
    x[4 * q + 2] = v.z;
    x[4 * q + 3] = v.w;
  }
}

// Dump sorted registers into region (wave-private), same rotated layout.
__device__ __forceinline__ void dump_x(float* wlds, int lane,
                                       const float* x) {
  float4* dst4 = (float4*)wlds;
#pragma unroll
  for (int q = 0; q < 8; ++q) {
    int wq = 8 * lane + ((q + lane) & 7);
    dst4[wq] =
        make_float4(x[4 * q], x[4 * q + 1], x[4 * q + 2], x[4 * q + 3]);
  }
}

// r6-proven merge-path selection over the two sorted halves in one region:
// [0..1023] ascending, [1024..2047] descending (both via swz layout).
// Lanes 0..4 find ranks {511,512,1023,1535,1536}; lane0 also reads mn/mx.
__device__ __forceinline__ void merge7(const float* wlds, int lane,
                                       float& val, float& mn, float& mx) {
  const int kk = (lane == 0) ? 511
               : (lane == 1) ? 512
               : (lane == 2) ? 1023
               : (lane == 3) ? 1535 : 1536;
  const int mtot = kk + 1;
  int lo = mtot - 1024; if (lo < 0) lo = 0;
  int hi = (mtot < 1024) ? mtot : 1024;
  for (int it = 0; it < 11; ++it) {
    const bool act = lo < hi;
    const int s = (lo + hi) >> 1;
    const int sa = (s < 1023) ? s : 1023;
    float Av = wlds[swz(sa)];
    Av = (s < 1024) ? Av : INFINITY;
    int bidx = mtot - s - 1;
    bidx = bidx < 0 ? 0 : (bidx > 1023 ? 1023 : bidx);
    const float Bv = wlds[swz(2047 - bidx)];
    const bool gg = act && (Bv > Av);
    if (gg) lo = s + 1;
    else if (act) hi = s;
  }
  {
    const int s = lo;
    const int ia = (s - 1 < 0) ? 0 : s - 1;
    const float fa = wlds[swz(ia)];
    const float fromA = (s > 0) ? fa : -INFINITY;
    const int bi = mtot - s - 1;
    const int ib = (bi < 0) ? 0 : bi;
    const float fb = wlds[swz(2047 - ib)];
    const float fromB = (bi >= 0) ? fb : -INFINITY;
    val = fmaxf(fromA, fromB);
  }
  if (lane == 0) {
    mn = fminf(wlds[swz(0)], wlds[swz(2047)]);
    mx = fmaxf(wlds[swz(1023)], wlds[swz(1024)]);
  }
}

__global__ __launch_bounds__(256, 2) void stat_kernel(
    const float* __restrict__ Fp, float* __restrict__ stat2) {
  __shared__ float lds[4 * LP]; // 32,896 B -> 4 blocks/CU
  const int g = blockIdx.x;     // 0..3071
  const int xcd = g & 7;
  const int mm = g >> 3;        // 0..383
  const int bc = xcd * 128 + mm / 3;
  const int grp = mm % 3;
  const int t = threadIdx.x;
  const int w = t >> 6;
  const int lane = t & 63;
  const int addr32 = ((lane ^ 32) << 2);
  const int j0 = grp * 8; // block covers columns j0..j0+7 (8 arrays)
  // wave w sorts two arrays: cx (round-1 region w), cy = cx+2 (round-2).
  const int cx = j0 + ((w < 2) ? w : w + 2); // {j0,j0+1,j0+4,j0+5}
  const int cy = cx + 2;                     // {j0+2,j0+3,j0+6,j0+7}

  // ---- staging round 1: columns {j0,j0+1,j0+4,j0+5} -> regions 0..3 ----
  float az[8], aw[8], bz[8], bw[8];
  const int rot = (t + ((t >> 5) << 2)) & 31; // swz(f) with f=it*256+t
  float* p0 = lds + (t & ~31) + rot;
  {
    const float* bbase = Fp + (size_t)bc * F_LEN * JTOT + j0;
#pragma unroll
    for (int it = 0; it < 8; ++it) {
      const int f = it * 256 + t;
      f4a va = *reinterpret_cast<const f4a*>(bbase + (size_t)f * JTOT);
      f4a vb = *reinterpret_cast<const f4a*>(bbase + (size_t)f * JTOT + 4);
      p0[it * 256] = va.x;          // region 0 = col j0
      p0[LP + it * 256] = va.y;     // region 1 = col j0+1
      p0[2 * LP + it * 256] = vb.x; // region 2 = col j0+4
      p0[3 * LP + it * 256] = vb.y; // region 3 = col j0+5
      az[it] = va.z; aw[it] = va.w; // cols j0+2, j0+3
      bz[it] = vb.z; bw[it] = vb.w; // cols j0+6, j0+7
    }
  }
  __syncthreads();

  float x[32], y[32];
  read_x(lds + w * LP, lane, x);
  __syncthreads();

  // ---- staging round 2: columns {j0+2,j0+3,j0+6,j0+7} -> regions 0..3 ----
  {
#pragma unroll
    for (int it = 0; it < 8; ++it) {
      p0[it * 256] = az[it];
      p0[LP + it * 256] = aw[it];
      p0[2 * LP + it * 256] = bz[it];
      p0[3 * LP + it * 256] = bw[it];
    }
  }
  __syncthreads();
  read_x(lds + w * LP, lane, y);
  // no further barriers: all tail LDS use is wave-private (region w).

  // ---- moments (two-pass central), both arrays interleaved ----
  float sx = 0.f, sy = 0.f;
#pragma unroll
  for (int e = 0; e < 32; ++e) { sx += x[e]; sy += y[e]; }
  wave_sum2(sx, sy, addr32);
  const float mx_m = sx * (1.0f / 2048.0f);
  const float my_m = sy * (1.0f / 2048.0f);

  float c2x = 0.f, c4x = 0.f, c2y = 0.f, c4y = 0.f;
#pragma unroll
  for (int e = 0; e < 32; ++e) {
    float dx = x[e] - mx_m, dy = y[e] - my_m;
    float ddx = dx * dx, ddy = dy * dy;
    c2x += ddx; c4x += ddx * ddx;
    c2y += ddy; c4y += ddy * ddy;
  }
  wave_sum2(c2x, c2y, addr32);
  wave_sum2(c4x, c4y, addr32);
  const float varx = c2x * (1.0f / 2047.0f); // ddof=1
  const float vary = c2y * (1.0f / 2047.0f);
  const float sdx = sqrtf(varx);
  const float sdy = sqrtf(vary);
  const float kurtx = (c4x * (1.0f / 2048.0f)) / (varx * varx) - 3.0f;
  const float kurty = (c4y * (1.0f / 2048.0f)) / (vary * vary) - 3.0f;

  // ---- bitonic stages 1..4: in-register, both arrays interleaved ----
#pragma unroll
  for (int kp = 1; kp <= 4; ++kp) {
    const int k = 1 << kp;
#pragma unroll
    for (int jp = kp - 1; jp >= 0; --jp) {
      const int st = 1 << jp;
#pragma unroll
      for (int e = 0; e < 32; ++e) {
        if ((e & st) == 0) {
          const bool up = ((e & k) == 0);
          {
            float a = x[e], b = x[e + st];
            float lo2 = fminf(a, b), hi2 = fmaxf(a, b);
            x[e] = up ? lo2 : hi2;
            x[e + st] = up ? hi2 : lo2;
          }
          {
            float a = y[e], b = y[e + st];
            float lo2 = fminf(a, b), hi2 = fmaxf(a, b);
            y[e] = up ? lo2 : hi2;
            y[e + st] = up ? hi2 : lo2;
          }
        }
      }
    }
  }

  // ---- stages 5..10: running sign-state Fst = direction ^ role ----
  unsigned Fst = 0u;
#pragma unroll
  for (int kp = 5; kp <= 10; ++kp) {
    const unsigned d = ((lane >> (kp - 5)) & 1) ? 0x80000000u : 0u;
#pragma unroll
    for (int jp = kp - 1; jp >= 5; --jp) {
      const int lm = 1 << (jp - 5); // 1,2,4,8,16
      const unsigned r = ((lane >> (jp - 5)) & 1) ? 0x80000000u : 0u;
      const unsigned tgt = d ^ r;
      const unsigned fl = tgt ^ Fst;
      Fst = tgt;
#pragma unroll
      for (int e = 0; e < 32; ++e) {
        x[e] = __uint_as_float(__float_as_uint(x[e]) ^ fl);
        y[e] = __uint_as_float(__float_as_uint(y[e]) ^ fl);
      }
#pragma unroll
      for (int e = 0; e < 32; ++e) {
        float ox = xpartner(x[e], lm, addr32);
        float oy = xpartner(y[e], lm, addr32);
        x[e] = fminf(x[e], -ox); // keeps min (role-0) / -max (role-1)
        y[e] = fminf(y[e], -oy);
      }
    }
    {
      const unsigned fl = d ^ Fst;
      Fst = d;
#pragma unroll
      for (int e = 0; e < 32; ++e) {
        x[e] = __uint_as_float(__float_as_uint(x[e]) ^ fl);
        y[e] = __uint_as_float(__float_as_uint(y[e]) ^ fl);
      }
    }
#pragma unroll
    for (int jp = 4; jp >= 0; --jp) {
      const int st = 1 << jp;
#pragma unroll
      for (int e = 0; e < 32; ++e) {
        if ((e & st) == 0) {
          {
            float a = x[e], b = x[e + st];
            x[e] = fminf(a, b);
            x[e + st] = fmaxf(a, b);
          }
          {
            float a = y[e], b = y[e + st];
            y[e] = fminf(a, b);
            y[e + st] = fmaxf(a, b);
          }
        }
      }
    }
  }
  // unflip (Fst = stage-10 direction = lane>=32): [0..1023] asc, rest desc.
#pragma unroll
  for (int e = 0; e < 32; ++e) {
    x[e] = __uint_as_float(__float_as_uint(x[e]) ^ Fst);
    y[e] = __uint_as_float(__float_as_uint(y[e]) ^ Fst);
  }

  // ---- wave-private dump + merge-path (region w), x then y ----
  float* wreg = lds + w * LP;
  float valx = 0.f, mnx = 0.f, mxx = 0.f;
  float valy = 0.f, mny = 0.f, mxy = 0.f;
  dump_x(wreg, lane, x);
  merge7(wreg, lane, valx, mnx, mxx);
  dump_x(wreg, lane, y); // in-order per-wave LDS: safe after merge reads
  merge7(wreg, lane, valy, mny, mxy);

  // ---- extraction + output ----
  const float a511x = __shfl(valx, 0, 64);
  const float a512x = __shfl(valx, 1, 64);
  const float amedx = __shfl(valx, 2, 64);
  const float a1535x = __shfl(valx, 3, 64);
  const float a1536x = __shfl(valx, 4, 64);
  const float a511y = __shfl(valy, 0, 64);
  const float a512y = __shfl(valy, 1, 64);
  const float amedy = __shfl(valy, 2, 64);
  const float a1535y = __shfl(valy, 3, 64);
  const float a1536y = __shfl(valy, 4, 64);

  if (lane == 0) {
    {
      const float q25 = 0.25f * a511x + 0.75f * a512x;   // pos = 511.75
      const float q75 = 0.75f * a1535x + 0.25f * a1536x; // pos = 1535.25
      const int jj = (cx < 12) ? cx : cx - 12;
      const int sb = (cx < 12) ? 0 : 8;
      float st8[8] = {mxx, q25, amedx, q75, mx_m, sdx, mxx - mnx, kurtx};
      float* o = stat2 + (bc * 16 + sb) * 12 + jj;
#pragma unroll
      for (int s2 = 0; s2 < 8; ++s2) o[s2 * 12] = st8[s2];
    }
    {
      const float q25 = 0.25f * a511y + 0.75f * a512y;
      const float q75 = 0.75f * a1535y + 0.25f * a1536y;
      const int jj = (cy < 12) ? cy : cy - 12;
      const int sb = (cy < 12) ? 0 : 8;
      float st8[8] = {mxy, q25, amedy, q75, my_m, sdy, mxy - mny, kurty};
      float* o = stat2 + (bc * 16 + sb) * 12 + jj;
#pragma unroll
      for (int s2 = 0; s2 < 8; ++s2) o[s2 * 12] = st8[s2];
    }
  }
}

// ---------------------------------------------------------------------------
// prep: M[k,c,s,j] = sum_e Wl[k,e*16+s] * W2[e,c,j]   (5*16*16*12 = 15360)
//       C[k] = bl[k] + sum_e b2[e] * sum_s Wl[k,e*16+s]
// logits[b,k] = sum_i M[k,i] * stat2[b,i] + C[k],  i = c*192 + s*12 + j
// ---------------------------------------------------------------------------
__global__ __launch_bounds__(256) void prep_kernel(
    const float* __restrict__ W2, const float* __restrict__ b2,
    const float* __restrict__ Wl, const float* __restrict__ bl,
    float* __restrict__ M, float* __restrict__ C) {
  const int g = blockIdx.x;
  const int t = threadIdx.x;
  if (g < 60) {
    const int id = g * 256 + t; // k*3072 + c*192 + s*12 + j
    const int k = id / 3072;
    const int r = id % 3072;
    const int c = r / 192;
    const int s = (r % 192) / 12;
    const int j = r % 12;
    const float* wl = Wl + k * 1024 + s;
    const float* w2 = W2 + c * 12 + j;
    float acc = 0.f;
#pragma unroll 8
    for (int e = 0; e < 64; ++e) acc += wl[e * 16] * w2[e * 192];
    M[id] = acc;
  } else if (t < 64) { // one wave computes C[0..4]
    const int e = t;
    const int addr32 = ((e ^ 32) << 2);
    for (int k = 0; k < 5; ++k) {
      const float* wl = Wl + k * 1024 + e * 16;
      float rs = 0.f;
#pragma unroll
      for (int s = 0; s < 16; ++s) rs += wl[s];
      float v = wave_sum(rs * b2[e], addr32);
      if (e == 0) C[k] = v + bl[k];
    }
  }
}

__global__ __launch_bounds__(256) void logits_kernel(
    const float* __restrict__ stat2, const float* __restrict__ M,
    const float* __restrict__ C, float* __restrict__ out) {
  __shared__ float s_red[20];
  const int b = blockIdx.x;
  const int t = threadIdx.x;
  const int lane = t & 63;
  const int w = t >> 6;
  const int addr32 = ((lane ^ 32) << 2);

  float acc[5] = {0.f, 0.f, 0.f, 0.f, 0.f};
#pragma unroll
  for (int ii = 0; ii < 12; ++ii) {
    const int i = ii * 256 + t;
    const float s = stat2[b * 3072 + i];
#pragma unroll
    for (int k = 0; k < 5; ++k) acc[k] += s * M[k * 3072 + i];
  }
#pragma unroll
  for (int k = 0; k < 5; ++k) acc[k] = wave_sum(acc[k], addr32);
  if (lane == 0) {
#pragma unroll
    for (int k = 0; k < 5; ++k) s_red[w * 5 + k] = acc[k];
  }
  __syncthreads();
  if (t < 5)
    out[b * 5 + t] =
        s_red[t] + s_red[5 + t] + s_red[10 + t] + s_red[15 + t] + C[t];
}

extern "C" void kernel_launch(void* const* d_in, const int* in_sizes, int n_in,
                              void* d_out, int out_size, void* d_ws,
                              size_t ws_size, hipStream_t stream) {
  const float* Fp = (const float*)d_in[0];
  // d_in[1] = W1, d_in[2] = b1 -> dead code in reference, unused.
  const float* W2 = (const float*)d_in[3];
  const float* b2 = (const float*)d_in[4];
  const float* Wl = (const float*)d_in[5];
  const float* bl = (const float*)d_in[6];
  float* out = (float*)d_out;

  float* stat2 = (float*)d_ws; // 1024*192 floats = 768 KB
  float* M = stat2 + 196608;   // 15360 floats
  float* C = M + 15360;        // 5 floats

  prep_kernel<<<61, 256, 0, stream>>>(W2, b2, Wl, bl, M, C);
  stat_kernel<<<3072, 256, 0, stream>>>(Fp, stat2);
  logits_kernel<<<64, 256, 0, stream>>>(stat2, M, C, out);
}